// Round 2
// baseline (400.270 us; speedup 1.0000x reference)
//
#include <hip/hip_runtime.h>

// Problem constants
#define BATCH     4096
#define N1        128     // n blocks (stage-1 block index, stage-2 K dim)
#define I1        64      // inputs per block 1 (stage-1 K dim)
#define MMID      64      // outputs per block 1 == n blocks 2
#define OOUT      128     // outputs per block 2
#define LDX       8192    // x row length
#define CSP       3.0f

typedef _Float16 half8  __attribute__((ext_vector_type(8)));
typedef float    float4_ __attribute__((ext_vector_type(4)));
typedef unsigned int uint4_ __attribute__((ext_vector_type(4)));

// ---------------------------------------------------------------------------
// Kernel 1: softmax prep.
//  conn1T[n][m][i] = softmax_i(3*c1[n][i][m])   (fp16, i contiguous)
//  conn2T[m][o][n] = softmax_n(3*c2[m][n][o])   (fp16, n contiguous)
// ---------------------------------------------------------------------------
__global__ __launch_bounds__(256) void prep_kernel(
    const float* __restrict__ c1, const float* __restrict__ c2,
    _Float16* __restrict__ conn1T, _Float16* __restrict__ conn2T) {
  int gid = blockIdx.x * 256 + threadIdx.x;
  if (gid < N1 * MMID) {
    // one thread per (n, m) column of c1
    const float* p = c1 + (size_t)(gid >> 6) * (I1 * MMID) + (gid & 63);
    float mx = -1e30f;
    for (int i = 0; i < I1; ++i) mx = fmaxf(mx, p[i * MMID]);
    mx *= CSP;
    float s = 0.f;
    for (int i = 0; i < I1; ++i) s += __expf(p[i * MMID] * CSP - mx);
    float inv = 1.0f / s;
    _Float16* dst = conn1T + (size_t)gid * I1;
    for (int i = 0; i < I1; ++i)
      dst[i] = (_Float16)(__expf(p[i * MMID] * CSP - mx) * inv);
  } else {
    int g = gid - N1 * MMID;
    if (g < MMID * OOUT) {
      // one thread per (m, o) column of c2
      const float* p = c2 + (size_t)(g >> 7) * (N1 * OOUT) + (g & 127);
      float mx = -1e30f;
      for (int i = 0; i < N1; ++i) mx = fmaxf(mx, p[i * OOUT]);
      mx *= CSP;
      float s = 0.f;
      for (int i = 0; i < N1; ++i) s += __expf(p[i * OOUT] * CSP - mx);
      float inv = 1.0f / s;
      _Float16* dst = conn2T + (size_t)g * N1;
      for (int i = 0; i < N1; ++i)
        dst[i] = (_Float16)(__expf(p[i * OOUT] * CSP - mx) * inv);
    }
  }
}

// ---------------------------------------------------------------------------
// Kernel 2: stage 1.  t[b][m][n] = sum_i x[b][n*64+i] * conn1T[n][m][i]
// Workgroup: 4 waves, b-tile = 16 rows, n-chunk = 32.
// Each wave owns one 16-wide m column tile; per n: 2 MFMA (K=64).
// D tiles buffered in padded LDS, flushed as 64B-contiguous runs of n.
// ---------------------------------------------------------------------------
#define S1_MSTRIDE 34            // fp16 elems per (b,m) row in LDS (32 + 2 pad)
#define S1_BSTRIDE (64 * S1_MSTRIDE + 4)  // 2180: +4 keeps quad groups on distinct banks

__global__ __launch_bounds__(256) void stage1_kernel(
    const float* __restrict__ x, const _Float16* __restrict__ conn1T,
    _Float16* __restrict__ t2) {
  __shared__ _Float16 lbuf[16 * S1_BSTRIDE];

  const int b0   = blockIdx.x * 16;
  const int n0   = blockIdx.y * 32;
  const int tid  = threadIdx.x;
  const int lane = tid & 63;
  const int wave = tid >> 6;         // m column tile
  const int row  = lane & 15;        // A row / B col / D col
  const int quad = lane >> 4;
  const int kk   = quad * 8;
  const int m_col = wave * 16 + row; // B-fragment column (m)

  const float* xrow = x + (size_t)(b0 + row) * LDX;

  for (int nn = 0; nn < 32; ++nn) {
    const int n = n0 + nn;
    // A fragments: 8 consecutive fp32 per K-half, convert to fp16
    const float* ap = xrow + n * I1 + kk;
    float4_ a0lo = *(const float4_*)(ap);
    float4_ a0hi = *(const float4_*)(ap + 4);
    float4_ a1lo = *(const float4_*)(ap + 32);
    float4_ a1hi = *(const float4_*)(ap + 36);
    half8 a0, a1;
#pragma unroll
    for (int j = 0; j < 4; ++j) {
      a0[j]     = (_Float16)a0lo[j];
      a0[j + 4] = (_Float16)a0hi[j];
      a1[j]     = (_Float16)a1lo[j];
      a1[j + 4] = (_Float16)a1hi[j];
    }
    // B fragments: 8 contiguous fp16 (i contiguous in conn1T)
    const _Float16* bp = conn1T + ((size_t)n * MMID + m_col) * I1 + kk;
    half8 bf0 = *(const half8*)(bp);
    half8 bf1 = *(const half8*)(bp + 32);

    float4_ acc = {0.f, 0.f, 0.f, 0.f};
    acc = __builtin_amdgcn_mfma_f32_16x16x32_f16(a0, bf0, acc, 0, 0, 0);
    acc = __builtin_amdgcn_mfma_f32_16x16x32_f16(a1, bf1, acc, 0, 0, 0);

    // D -> LDS (fp16). D[row = quad*4+r][col = row]
#pragma unroll
    for (int r = 0; r < 4; ++r) {
      int bl = quad * 4 + r;
      lbuf[bl * S1_BSTRIDE + m_col * S1_MSTRIDE + nn] = (_Float16)acc[r];
    }
  }
  __syncthreads();

  // Flush: each thread handles 4 (b,m) pairs; 32 halfs (64B) contiguous in n
  // per pair -> four 16B stores forming one 64B-aligned run.
#pragma unroll
  for (int it = 0; it < 4; ++it) {
    int p  = tid + it * 256;     // 0..1023
    int bl = p >> 6;
    int mm = p & 63;
    const unsigned int* src =
        (const unsigned int*)(lbuf + bl * S1_BSTRIDE + mm * S1_MSTRIDE);
    uint4_ v0 = {src[0],  src[1],  src[2],  src[3]};
    uint4_ v1 = {src[4],  src[5],  src[6],  src[7]};
    uint4_ v2 = {src[8],  src[9],  src[10], src[11]};
    uint4_ v3 = {src[12], src[13], src[14], src[15]};
    _Float16* dst = t2 + ((size_t)(b0 + bl) * MMID + mm) * N1 + n0;
    *(uint4_*)(dst)      = v0;
    *(uint4_*)(dst + 8)  = v1;
    *(uint4_*)(dst + 16) = v2;
    *(uint4_*)(dst + 24) = v3;
  }
}

// ---------------------------------------------------------------------------
// Kernel 3: stage 2.  out[b][m*128+o] = sum_n t[b][m][n] * conn2T[m][o][n]
// Workgroup: 4 waves, b-tile = 64 (16 per wave), one m per workgroup.
// K = 128 (4 MFMA k-steps), 8 o column tiles per wave.
// ---------------------------------------------------------------------------
__global__ __launch_bounds__(256) void stage2_kernel(
    const _Float16* __restrict__ t2, const _Float16* __restrict__ conn2T,
    float* __restrict__ out) {
  const int m    = blockIdx.x;       // 0..63
  const int b0   = blockIdx.y * 64;
  const int tid  = threadIdx.x;
  const int lane = tid & 63;
  const int wave = tid >> 6;
  const int row  = lane & 15;
  const int quad = lane >> 4;

  const int b = b0 + wave * 16 + row;                 // A row
  const _Float16* arow  = t2 + ((size_t)b * MMID + m) * N1;
  const _Float16* bbase = conn2T + (size_t)m * OOUT * N1;

  float4_ acc[8];
#pragma unroll
  for (int ot = 0; ot < 8; ++ot) acc[ot] = (float4_){0.f, 0.f, 0.f, 0.f};

#pragma unroll
  for (int ks = 0; ks < 4; ++ks) {
    const int kk = ks * 32 + quad * 8;
    half8 a = *(const half8*)(arow + kk);
#pragma unroll
    for (int ot = 0; ot < 8; ++ot) {
      const int o = ot * 16 + row;
      half8 bf = *(const half8*)(bbase + (size_t)o * N1 + kk);
      acc[ot] = __builtin_amdgcn_mfma_f32_16x16x32_f16(a, bf, acc[ot], 0, 0, 0);
    }
  }

  // Epilogue: fp32 stores, 16 lanes x 4B = 64B contiguous per (ot, r)
#pragma unroll
  for (int ot = 0; ot < 8; ++ot) {
#pragma unroll
    for (int r = 0; r < 4; ++r) {
      const int bb = b0 + wave * 16 + quad * 4 + r;
      const int o  = ot * 16 + row;
      out[(size_t)bb * LDX + m * OOUT + o] = acc[ot][r];
    }
  }
}

// ---------------------------------------------------------------------------
extern "C" void kernel_launch(void* const* d_in, const int* in_sizes, int n_in,
                              void* d_out, int out_size, void* d_ws, size_t ws_size,
                              hipStream_t stream) {
  (void)in_sizes; (void)n_in; (void)out_size; (void)ws_size;
  const float* x  = (const float*)d_in[0];
  const float* c1 = (const float*)d_in[1];
  const float* c2 = (const float*)d_in[2];
  float* out = (float*)d_out;

  // Workspace layout (fp16 elements):
  //   conn1T: 128*64*64   =   524,288
  //   conn2T: 64*128*128  = 1,048,576
  //   t2:     4096*64*128 = 33,554,432
  _Float16* conn1T = (_Float16*)d_ws;
  _Float16* conn2T = conn1T + (size_t)N1 * MMID * I1;
  _Float16* t2     = conn2T + (size_t)MMID * OOUT * N1;

  prep_kernel<<<64, 256, 0, stream>>>(c1, c2, conn1T, conn2T);
  stage1_kernel<<<dim3(BATCH / 16, N1 / 32), 256, 0, stream>>>(x, conn1T, t2);
  stage2_kernel<<<dim3(MMID, BATCH / 64), 256, 0, stream>>>(t2, conn2T, out);
}

// Round 3
// 359.273 us; speedup vs baseline: 1.1141x; 1.1141x over previous
//
#include <hip/hip_runtime.h>

// Problem constants
#define BATCH     4096
#define N1        128     // n blocks (stage-1 block index, stage-2 K dim)
#define I1        64      // inputs per block 1 (stage-1 K dim)
#define MMID      64      // outputs per block 1 == n blocks 2
#define OOUT      128     // outputs per block 2
#define LDX       8192    // x row length
#define CSP       3.0f

typedef _Float16 half8  __attribute__((ext_vector_type(8)));
typedef float    float4_ __attribute__((ext_vector_type(4)));
typedef unsigned int uint4_ __attribute__((ext_vector_type(4)));

// ---------------------------------------------------------------------------
// Kernel 1: softmax prep.
//  conn1T[n][m][i] = softmax_i(3*c1[n][i][m])   (fp16, i contiguous)
//  conn2T[m][o][n] = softmax_n(3*c2[m][n][o])   (fp16, n contiguous)
// ---------------------------------------------------------------------------
__global__ __launch_bounds__(256) void prep_kernel(
    const float* __restrict__ c1, const float* __restrict__ c2,
    _Float16* __restrict__ conn1T, _Float16* __restrict__ conn2T) {
  int gid = blockIdx.x * 256 + threadIdx.x;
  if (gid < N1 * MMID) {
    const float* p = c1 + (size_t)(gid >> 6) * (I1 * MMID) + (gid & 63);
    float mx = -1e30f;
    for (int i = 0; i < I1; ++i) mx = fmaxf(mx, p[i * MMID]);
    mx *= CSP;
    float s = 0.f;
    for (int i = 0; i < I1; ++i) s += __expf(p[i * MMID] * CSP - mx);
    float inv = 1.0f / s;
    _Float16* dst = conn1T + (size_t)gid * I1;
    for (int i = 0; i < I1; ++i)
      dst[i] = (_Float16)(__expf(p[i * MMID] * CSP - mx) * inv);
  } else {
    int g = gid - N1 * MMID;
    if (g < MMID * OOUT) {
      const float* p = c2 + (size_t)(g >> 7) * (N1 * OOUT) + (g & 127);
      float mx = -1e30f;
      for (int i = 0; i < N1; ++i) mx = fmaxf(mx, p[i * OOUT]);
      mx *= CSP;
      float s = 0.f;
      for (int i = 0; i < N1; ++i) s += __expf(p[i * OOUT] * CSP - mx);
      float inv = 1.0f / s;
      _Float16* dst = conn2T + (size_t)g * N1;
      for (int i = 0; i < N1; ++i)
        dst[i] = (_Float16)(__expf(p[i * OOUT] * CSP - mx) * inv);
    }
  }
}

// ---------------------------------------------------------------------------
// Kernel 2: stage 1.  t[b][m][n] = sum_i x[b][n*64+i] * conn1T[n][m][i]
// Block: 4 waves, b-tile 16, n-chunk 16. Wave w owns n = n0+w*4 .. +4 and
// computes ALL 4 m-tiles for them (A loaded once per n per block).
// t2 layout: [chunk c][b][m][16 n]  -> flush writes fully contiguous.
// LDS ~37 KB -> 4 blocks/CU.
// ---------------------------------------------------------------------------
#define S1_NC      16
#define S1_MSTRIDE 18                      // 16 + 2 pad (halfs)
#define S1_BSTRIDE (64 * S1_MSTRIDE + 4)   // 1156 halfs per b row

__global__ __launch_bounds__(256) void stage1_kernel(
    const float* __restrict__ x, const _Float16* __restrict__ conn1T,
    _Float16* __restrict__ t2) {
  __shared__ _Float16 lbuf[16 * S1_BSTRIDE];

  const int b0   = blockIdx.x * 16;
  const int c    = blockIdx.y;          // n-chunk index (16 n per chunk)
  const int n0   = c * S1_NC;
  const int tid  = threadIdx.x;
  const int lane = tid & 63;
  const int wave = tid >> 6;
  const int row  = lane & 15;           // A row (b) / B col (m)
  const int quad = lane >> 4;
  const int kk   = quad * 8;

  const float* xrow = x + (size_t)(b0 + row) * LDX;

#pragma unroll 2
  for (int j = 0; j < 4; ++j) {
    const int nn = wave * 4 + j;
    const int n  = n0 + nn;
    // A fragments (shared across the 4 m-tiles): fp32 -> fp16
    const float* ap = xrow + n * I1 + kk;
    float4_ a0lo = *(const float4_*)(ap);
    float4_ a0hi = *(const float4_*)(ap + 4);
    float4_ a1lo = *(const float4_*)(ap + 32);
    float4_ a1hi = *(const float4_*)(ap + 36);
    half8 a0, a1;
#pragma unroll
    for (int u = 0; u < 4; ++u) {
      a0[u]     = (_Float16)a0lo[u];
      a0[u + 4] = (_Float16)a0hi[u];
      a1[u]     = (_Float16)a1lo[u];
      a1[u + 4] = (_Float16)a1hi[u];
    }
    // B fragments for all 4 m-tiles
    const _Float16* bn = conn1T + (size_t)n * (MMID * I1);
    half8 bf0[4], bf1[4];
#pragma unroll
    for (int mt = 0; mt < 4; ++mt) {
      const _Float16* bp = bn + (mt * 16 + row) * I1 + kk;
      bf0[mt] = *(const half8*)(bp);
      bf1[mt] = *(const half8*)(bp + 32);
    }
#pragma unroll
    for (int mt = 0; mt < 4; ++mt) {
      float4_ acc = {0.f, 0.f, 0.f, 0.f};
      acc = __builtin_amdgcn_mfma_f32_16x16x32_f16(a0, bf0[mt], acc, 0, 0, 0);
      acc = __builtin_amdgcn_mfma_f32_16x16x32_f16(a1, bf1[mt], acc, 0, 0, 0);
      // D[row = quad*4+r (b)][col = row (m)]
#pragma unroll
      for (int r = 0; r < 4; ++r) {
        lbuf[(quad * 4 + r) * S1_BSTRIDE + (mt * 16 + row) * S1_MSTRIDE + nn] =
            (_Float16)acc[r];
      }
    }
  }
  __syncthreads();

  // Flush: 1024 (b,m) pairs, 16 halfs (32B) each; lanes cover consecutive m
  // -> wave writes 2 KB dense per pass.
#pragma unroll
  for (int it = 0; it < 4; ++it) {
    int p  = tid + it * 256;
    int bl = p >> 6;          // b offset in tile
    int mm = p & 63;          // m
    const unsigned int* src =
        (const unsigned int*)(lbuf + bl * S1_BSTRIDE + mm * S1_MSTRIDE);
    uint4_ v0 = {src[0], src[1], src[2], src[3]};
    uint4_ v1 = {src[4], src[5], src[6], src[7]};
    _Float16* dst =
        t2 + (((size_t)c * BATCH + b0 + bl) * MMID + mm) * S1_NC;
    *(uint4_*)(dst)     = v0;
    *(uint4_*)(dst + 8) = v1;
  }
}

// ---------------------------------------------------------------------------
// Kernel 3: stage 2.  out[b][m*128+o] = sum_n t[b][m][n] * conn2T[m][o][n]
// Block: 4 waves, one m, b-tile 64 (16 per wave). All 36 loads hoisted
// before the MFMA chain (A from HBM issued first, B L2-hot).
// ---------------------------------------------------------------------------
__global__ __launch_bounds__(256) void stage2_kernel(
    const _Float16* __restrict__ t2, const _Float16* __restrict__ conn2T,
    float* __restrict__ out) {
  const int m    = blockIdx.x;       // 0..63
  const int b0   = blockIdx.y * 64;
  const int tid  = threadIdx.x;
  const int lane = tid & 63;
  const int wave = tid >> 6;
  const int row  = lane & 15;
  const int quad = lane >> 4;

  const int b = b0 + wave * 16 + row;     // A row
  // A fragments: n = ks*32 + quad*8 + [0,8) -> chunk c = ks*2 + (quad>>1)
  half8 a[4];
#pragma unroll
  for (int ks = 0; ks < 4; ++ks) {
    const int cc  = ks * 2 + (quad >> 1);
    const int off = (quad & 1) * 8;
    a[ks] = *(const half8*)(
        t2 + (((size_t)cc * BATCH + b) * MMID + m) * S1_NC + off);
  }
  // B fragments (conn2T slice for m: 32 KB, L2-resident)
  const _Float16* bbase = conn2T + (size_t)m * OOUT * N1;
  half8 bf[4][8];
#pragma unroll
  for (int ks = 0; ks < 4; ++ks)
#pragma unroll
    for (int ot = 0; ot < 8; ++ot)
      bf[ks][ot] =
          *(const half8*)(bbase + (size_t)(ot * 16 + row) * N1 + ks * 32 + quad * 8);

  float4_ acc[8];
#pragma unroll
  for (int ot = 0; ot < 8; ++ot) acc[ot] = (float4_){0.f, 0.f, 0.f, 0.f};
#pragma unroll
  for (int ks = 0; ks < 4; ++ks)
#pragma unroll
    for (int ot = 0; ot < 8; ++ot)
      acc[ot] = __builtin_amdgcn_mfma_f32_16x16x32_f16(a[ks], bf[ks][ot], acc[ot], 0, 0, 0);

  // Epilogue: fp32 stores, 16 lanes x 4B = 64B contiguous per (ot, r)
#pragma unroll
  for (int ot = 0; ot < 8; ++ot) {
#pragma unroll
    for (int r = 0; r < 4; ++r) {
      const int bb = b0 + wave * 16 + quad * 4 + r;
      const int o  = ot * 16 + row;
      out[(size_t)bb * LDX + m * OOUT + o] = acc[ot][r];
    }
  }
}

// ---------------------------------------------------------------------------
extern "C" void kernel_launch(void* const* d_in, const int* in_sizes, int n_in,
                              void* d_out, int out_size, void* d_ws, size_t ws_size,
                              hipStream_t stream) {
  (void)in_sizes; (void)n_in; (void)out_size; (void)ws_size;
  const float* x  = (const float*)d_in[0];
  const float* c1 = (const float*)d_in[1];
  const float* c2 = (const float*)d_in[2];
  float* out = (float*)d_out;

  // Workspace (fp16 elems): conn1T 524288, conn2T 1048576, t2 33554432
  _Float16* conn1T = (_Float16*)d_ws;
  _Float16* conn2T = conn1T + (size_t)N1 * MMID * I1;
  _Float16* t2     = conn2T + (size_t)MMID * OOUT * N1;

  prep_kernel<<<64, 256, 0, stream>>>(c1, c2, conn1T, conn2T);
  stage1_kernel<<<dim3(BATCH / 16, N1 / S1_NC), 256, 0, stream>>>(x, conn1T, t2);
  stage2_kernel<<<dim3(MMID, BATCH / 64), 256, 0, stream>>>(t2, conn2T, out);
}